// Round 12
// baseline (4052.198 us; speedup 1.0000x reference)
//
#include <hip/hip_runtime.h>

// Two-layer tanh RNN, H=32, B=64, T=16384. Latency-bound sequential scan.
//
// Round-12: R10's proven 2-wave producer/consumer split (3842 us), with every
// 32-FMA row dot packed into 16 v_pk_fma_f32 + 2 v_pk_add_f32 (fp32 packed
// math is full-rate on CDNA4; compiler never auto-packs fp32). The ds_write +
// 8x ds_read_b128 broadcast is retained (R11 showed bpermute is not better:
// DS op count vs latency nets out). b128 read quads are even-aligned; their
// two sub-pairs feed pk_fma as aligned subregisters (no repack movs).
// Wave A (h0 chain): lower lanes Whh0 rows, upper lanes Wih1 rows publishing
// u(t-1)=b1+Wih1.h0n(t-1) to the double-buffered window ring. Wave B (h1
// chain, one window behind): lower Whh1 (consumes u), upper Wout (out(t-1)
// free). One barrier per 32-step window; R10 indexing/epilogues unchanged.

#define T_LEN 16384
#define B_SZ  64
#define NW    (T_LEN / 32)   // 512 windows

typedef float v2f __attribute__((ext_vector_type(2)));
typedef float v4f __attribute__((ext_vector_type(4)));

__device__ __forceinline__ void pk_fma(v2f& d, v2f a, v2f b) {
  asm("v_pk_fma_f32 %0, %1, %2, %0" : "+v"(d) : "v"(a), "v"(b));
}
__device__ __forceinline__ void pk_add(v2f& d, v2f a) {
  asm("v_pk_add_f32 %0, %0, %1" : "+v"(d) : "v"(a));
}

// acc = INIT0 + sum_j W2[j-pair] * hbase[j]  (32-long dot, packed)
#define DOT32(HBASE, W2, INIT0) ({                                        \
  v2f q0_ = {(INIT0), 0.f}, q1_ = {0.f, 0.f}, q2_ = {0.f, 0.f}, q3_ = {0.f, 0.f}; \
  const v4f* hp_ = (const v4f*)(HBASE);                                   \
  _Pragma("unroll")                                                       \
  for (int k_ = 0; k_ < 8; ++k_) {                                        \
    v4f hv_ = hp_[k_];                                                    \
    v2f lo_ = __builtin_shufflevector(hv_, hv_, 0, 1);                    \
    v2f hi_ = __builtin_shufflevector(hv_, hv_, 2, 3);                    \
    if (k_ & 1) { pk_fma(q2_, (W2)[2*k_], lo_); pk_fma(q3_, (W2)[2*k_+1], hi_); } \
    else        { pk_fma(q0_, (W2)[2*k_], lo_); pk_fma(q1_, (W2)[2*k_+1], hi_); } \
  }                                                                       \
  pk_add(q0_, q2_); pk_add(q1_, q3_);                                     \
  (q0_.x + q0_.y) + (q1_.x + q1_.y); })

__device__ __forceinline__ float rl(float v, int lane) {
  return __int_as_float(__builtin_amdgcn_readlane(__float_as_int(v), lane));
}

__device__ __forceinline__ float tanh_fast(float v) {
  // tanh(x) = 1 - 2/(exp(2x)+1); saturates correctly at +/-inf.
  float e = __expf(2.0f * v);
  return 1.0f - __fdividef(2.0f, e + 1.0f);
}

__global__ __launch_bounds__(128, 1) void rnn2_kernel(
    const float* __restrict__ x,    const float* __restrict__ hs,
    const float* __restrict__ Wih0, const float* __restrict__ Whh0,
    const float* __restrict__ bih0, const float* __restrict__ bhh0,
    const float* __restrict__ Wih1, const float* __restrict__ Whh1,
    const float* __restrict__ bih1, const float* __restrict__ bhh1,
    const float* __restrict__ Wout, const float* __restrict__ bout,
    float* __restrict__ out)
{
  __shared__ __align__(16) float h0buf[64];      // wave-A private; [0..31] = h0n
  __shared__ __align__(16) float h1buf[64];      // wave-B private; [0..31] = h1n
  __shared__ __align__(16) float uwin[2][2048];  // A->B; slot t2: [t2*64+32+r]=u[r]

  const int  tid = (int)threadIdx.x;
  const int  wv  = tid >> 6;           // 0 = wave A (h0), 1 = wave B (h1)
  const int  m   = tid & 63;
  const int  r   = m & 31;
  const bool up  = (m >= 32);
  const int  b   = (int)blockIdx.x;

  // One 32-float weight row per lane, stored as 16 packed pairs:
  //  A: lower = Whh0 row r, upper = Wih1 row r.  B: lower = Whh1 row r, upper = Wout.
  const float* wrow;
  if (wv == 0) wrow = up ? (Wih1 + r * 32) : (Whh0 + r * 32);
  else         wrow = up ? Wout            : (Whh1 + r * 32);
  v2f w2[16];
#pragma unroll
  for (int k = 0; k < 8; ++k) {
    float4 q = ((const float4*)wrow)[k];
    w2[2*k]   = v2f{q.x, q.y};
    w2[2*k+1] = v2f{q.z, q.w};
  }

  float xw = 0.f, bini = 0.f;
  if (wv == 0) {
    if (!up) { xw = Wih0[r]; bini = bih0[r] + bhh0[r]; }  // layer-0 bias
    else     { bini = bih1[r] + bhh1[r]; }                // b1 folded into u
  }
  const float bo = bout[0];

  // Init private broadcasts: all-lane writes, lower 32 meaningful.
  if (wv == 0) h0buf[m] = hs[b * 32 + r];
  else         h1buf[m] = hs[2048 + b * 32 + r];
  __syncthreads();

  const float* xb   = x + (size_t)b * T_LEN;
  float*       outp = out + (size_t)b * T_LEN;       // outs[b*T + t]
  float*       hf   = out + (size_t)B_SZ * T_LEN;    // h_final [2,B,H]

  float h0last = 0.f, h1last = 0.f, obuf = 0.f;

  for (int wdx = 0; wdx <= NW; ++wdx) {
    if (wv == 0) {
      if (wdx < NW) {
        const int tb = 32 * wdx;
        float xchunk = xb[tb + r];            // lanes hold x(tb .. tb+31)
        float* ub = &uwin[wdx & 1][0];
#pragma unroll 4
        for (int t2 = 0; t2 < 32; ++t2) {
          // Pre-write broadcast: h0buf = h0n(tb+t2-1).
          float acc = DOT32(h0buf, w2, bini); // lower: b0+Whh0.h0; upper: u(t-1)[r]
          ub[t2 * 64 + m] = acc;              // all-lane publish (upper half used)
          float xv  = rl(xchunk, t2);
          float h0n = tanh_fast(fmaf(xv, xw, acc));
          h0buf[m] = h0n;                     // all-lane; [0..31] = h0n(tb+t2)
          h0last = h0n;
        }
      }
    } else {
      if (wdx >= 1) {
        const int wb = wdx - 1;               // steps t = 32*wb-1 .. 32*wb+30
        const float* ub = &uwin[wb & 1][0];
#pragma unroll 4
        for (int t2 = 0; t2 < 32; ++t2) {
          const int t = 32 * wb - 1 + t2;
          float uval = ub[t2 * 64 + 32 + r];  // u(t)[r]
          float acc = DOT32(h1buf, w2, up ? 0.f : uval);
          float h1n = tanh_fast(acc);         // lower: h1n(t); upper: junk
          obuf = (m == 32 + t2) ? acc : obuf; // upper lane t2 keeps out(t-1)-bo
          if (t >= 0) {                       // uniform: skips only wb=0,t2=0
            h1buf[m] = h1n;                   // all-lane; [0..31] = h1n(t)
            h1last = h1n;
          }
        }
        const int idx = 32 * wb - 2 + r;      // upper lane r holds out(idx)
        if (up && idx >= 0) outp[idx] = obuf + bo;   // coalesced 32-store
      }
    }
    __syncthreads();   // window handoff (uwin parity swap)
  }

  // Epilogue 1 (wave A): publish u(T-1) from h0n(T-1) into uwin[0].
  if (wv == 0) {
    float acc = DOT32(h0buf, w2, bini);       // h0buf = h0n(T-1)
    uwin[0][m] = acc;                         // [32+r] = u(T-1)[r]
  }
  __syncthreads();

  // Epilogue 2 (wave B): h1n(T-1), out(T-2), out(T-1).
  if (wv == 1) {
    float uT  = uwin[0][32 + r];
    float acc = DOT32(h1buf, w2, up ? 0.f : uT);   // h1buf = h1n(T-2)
    if (m == 32) outp[T_LEN - 2] = acc + bo;  // out(T-2) = Wout.h1n(T-2)+bo
    float h1T = tanh_fast(acc);               // lower: h1n(T-1)
    h1buf[m] = h1T;                           // all-lane write
    float acc2 = DOT32(h1buf, w2, 0.f);       // h1n(T-1) broadcast (in-order)
    if (m == 32) outp[T_LEN - 1] = acc2 + bo;
    if (!up) hf[2048 + b * 32 + r] = h1T;     // h_final layer 1
  } else {
    if (!up) hf[b * 32 + r] = h0last;         // h_final layer 0
  }
}

extern "C" void kernel_launch(void* const* d_in, const int* in_sizes, int n_in,
                              void* d_out, int out_size, void* d_ws, size_t ws_size,
                              hipStream_t stream) {
  rnn2_kernel<<<dim3(B_SZ), dim3(128), 0, stream>>>(
      (const float*)d_in[0],  (const float*)d_in[1],  (const float*)d_in[2],
      (const float*)d_in[3],  (const float*)d_in[4],  (const float*)d_in[5],
      (const float*)d_in[6],  (const float*)d_in[7],  (const float*)d_in[8],
      (const float*)d_in[9],  (const float*)d_in[10], (const float*)d_in[11],
      (float*)d_out);
}

// Round 13
// 4051.897 us; speedup vs baseline: 1.0001x; 1.0001x over previous
//
#include <hip/hip_runtime.h>

// Two-layer tanh RNN, H=32, B=64, T=16384. Latency-bound sequential scan.
//
// Round-13: SPLIT THE TWO CHAINS ONTO SEPARATE CUs. R10/R11/R12 all plateau
// at ~560-590 cyc/step; R12 (half the VALU issue) was neutral -> latency-
// chain bound, and the un-modeled cost is two waves sharing one CU's in-order
// DS pipe + a per-window __syncthreads. Here: 128 blocks x 1 wave. Blocks
// 0..63 = wave A (h0 chain; lower lanes Whh0 rows, upper lanes Wih1 rows
// publishing u(t-1)=b1+Wih1.h0n(t-1) via coalesced GLOBAL stores - off the
// DS pipe). Blocks 64..127 = wave B (h1 chain, one window behind; lower
// lanes Whh1 consume prefetched u, upper lanes Wout -> out(t-1) free).
// Handoff: 8-window u-ring in d_ws + per-batch release/acquire flags
// (__hip_atomic_*, AGENT scope - correct across XCDs), with backpressure.
// No __syncthreads anywhere; each wave owns its DS pipe (9 ops/step).
// Poisoned flags (0xAAAAAAAA) are negative ints -> spins are safe.

#define T_LEN 16384
#define B_SZ  64
#define NW    (T_LEN / 32)   // 512 windows
#define RING  8

__device__ __forceinline__ float rl(float v, int lane) {
  return __int_as_float(__builtin_amdgcn_readlane(__float_as_int(v), lane));
}

__device__ __forceinline__ float tanh_fast(float v) {
  // tanh(x) = 1 - 2/(exp(2x)+1); saturates correctly at +/-inf.
  float e = __expf(2.0f * v);
  return 1.0f - __fdividef(2.0f, e + 1.0f);
}

// acc = init + sum_j w[j] * hbuf[j]  (R10's proven float4-broadcast dot)
#define DOT32(HBUF, W, INIT) ({                                   \
  float a0_ = (INIT), a1_ = 0.f, a2_ = 0.f, a3_ = 0.f;            \
  const float4* hp_ = (const float4*)(HBUF);                      \
  _Pragma("unroll")                                               \
  for (int k_ = 0; k_ < 8; ++k_) {                                \
    float4 hv_ = hp_[k_];                                         \
    a0_ = fmaf((W)[4*k_],   hv_.x, a0_);                          \
    a1_ = fmaf((W)[4*k_+1], hv_.y, a1_);                          \
    a2_ = fmaf((W)[4*k_+2], hv_.z, a2_);                          \
    a3_ = fmaf((W)[4*k_+3], hv_.w, a3_);                          \
  }                                                               \
  (a0_ + a1_) + (a2_ + a3_); })

__global__ __launch_bounds__(64, 1) void rnn2_split(
    const float* __restrict__ x,    const float* __restrict__ hs,
    const float* __restrict__ Wih0, const float* __restrict__ Whh0,
    const float* __restrict__ bih0, const float* __restrict__ bhh0,
    const float* __restrict__ Wih1, const float* __restrict__ Whh1,
    const float* __restrict__ bih1, const float* __restrict__ bhh1,
    const float* __restrict__ Wout, const float* __restrict__ bout,
    float* __restrict__ out, int* __restrict__ aflag,
    int* __restrict__ bflag, float* __restrict__ uG)
{
  __shared__ __align__(16) float hbuf[64];   // [0..31] = live h state

  const int  m   = (int)threadIdx.x;
  const int  r   = m & 31;
  const bool up  = (m >= 32);
  const int  blk = (int)blockIdx.x;
  const int  b   = blk & 63;
  const bool isB = (blk >= 64);

  // One 32-float weight row per lane:
  //  A: lower = Whh0 row r, upper = Wih1 row r.  B: lower = Whh1 row r, upper = Wout.
  const float* wrow;
  if (!isB) wrow = up ? (Wih1 + r * 32) : (Whh0 + r * 32);
  else      wrow = up ? Wout            : (Whh1 + r * 32);
  float w[32];
#pragma unroll
  for (int k = 0; k < 8; ++k) {
    float4 q = ((const float4*)wrow)[k];
    w[4*k] = q.x; w[4*k+1] = q.y; w[4*k+2] = q.z; w[4*k+3] = q.w;
  }

  float* uB   = uG + (size_t)b * (RING * 1024);   // ring: slot*1024 + t2*32 + r
  float* outp = out + (size_t)b * T_LEN;          // outs[b*T + t]
  float* hf   = out + (size_t)B_SZ * T_LEN;       // h_final [2,B,H]

  if (!isB) {
    // ================= Wave A: h0 chain (+ u publication) =================
    float xw = 0.f, bini;
    if (!up) { xw = Wih0[r]; bini = bih0[r] + bhh0[r]; }
    else     { bini = bih1[r] + bhh1[r]; }          // b1 folded into u

    hbuf[m] = hs[b * 32 + r];                        // all-lane init write
    const float* xb = x + (size_t)b * T_LEN;
    float h0last = 0.f;

    for (int wdx = 0; wdx < NW; ++wdx) {
      if (wdx >= RING) {                             // ring backpressure
        while (__hip_atomic_load(&bflag[b], __ATOMIC_ACQUIRE,
                                 __HIP_MEMORY_SCOPE_AGENT) < wdx - RING + 1) {}
      }
      const int tb = 32 * wdx;
      float xchunk = xb[tb + r];                     // x(tb..tb+31)
      float* us = uB + (wdx & (RING - 1)) * 1024;
#pragma unroll 4
      for (int t2 = 0; t2 < 32; ++t2) {
        // hbuf = h0n(tb+t2-1); broadcast dot (8x ds_read_b128).
        float acc = DOT32(hbuf, w, bini);  // lower: b0+Whh0.h0; upper: u(t-1)[r]
        const int ti = tb + t2 - 1;
        if (up && ti >= 0) us[t2 * 32 + r] = acc;    // coalesced 128B store
        float xv  = rl(xchunk, t2);
        float h0n = tanh_fast(fmaf(xv, xw, acc));
        hbuf[m] = h0n;                               // all-lane; [0..31] live
        h0last = h0n;
      }
      __hip_atomic_store(&aflag[b], wdx + 1, __ATOMIC_RELEASE,
                         __HIP_MEMORY_SCOPE_AGENT);
    }

    // Epilogue: publish u(T-1) into slot 0, position 0.
    while (__hip_atomic_load(&bflag[b], __ATOMIC_ACQUIRE,
                             __HIP_MEMORY_SCOPE_AGENT) < NW - RING + 1) {}
    float acc = DOT32(hbuf, w, bini);                // hbuf = h0n(T-1)
    if (up) uB[r] = acc;                             // u(T-1)[r]
    __hip_atomic_store(&aflag[b], NW + 1, __ATOMIC_RELEASE,
                       __HIP_MEMORY_SCOPE_AGENT);
    if (!up) hf[b * 32 + r] = h0last;                // h_final layer 0
  } else {
    // ================= Wave B: h1 chain (+ output) =================
    hbuf[m] = hs[2048 + b * 32 + r];                 // all-lane init write
    const float bo = bout[0];
    float obuf = 0.f, h1last = 0.f;

    for (int wb = 0; wb < NW; ++wb) {
      while (__hip_atomic_load(&aflag[b], __ATOMIC_ACQUIRE,
                               __HIP_MEMORY_SCOPE_AGENT) < wb + 1) {}
      const float* us = uB + (wb & (RING - 1)) * 1024;
      float ubuf[32];
#pragma unroll
      for (int t2 = 0; t2 < 32; ++t2) ubuf[t2] = us[t2 * 32 + r];  // 32 coalesced loads
#pragma unroll 4
      for (int t2 = 0; t2 < 32; ++t2) {
        const int t = 32 * wb - 1 + t2;
        float acc = DOT32(hbuf, w, up ? 0.f : ubuf[t2]);
        float h1n = tanh_fast(acc);                  // lower: h1n(t)
        obuf = (m == 32 + t2) ? acc : obuf;          // upper lane t2: out(t-1)-bo
        if (t >= 0) {                                // skips only wb=0,t2=0
          hbuf[m] = h1n;
          h1last = h1n;
        }
      }
      const int idx = 32 * wb - 2 + r;               // upper lane r holds out(idx)
      if (up && idx >= 0) outp[idx] = obuf + bo;     // coalesced 32-store
      __hip_atomic_store(&bflag[b], wb + 1, __ATOMIC_RELEASE,
                         __HIP_MEMORY_SCOPE_AGENT);
    }

    // Epilogue: h1n(T-1), out(T-2), out(T-1).
    while (__hip_atomic_load(&aflag[b], __ATOMIC_ACQUIRE,
                             __HIP_MEMORY_SCOPE_AGENT) < NW + 1) {}
    float uT  = uB[r];                               // u(T-1)[r]
    float acc = DOT32(hbuf, w, up ? 0.f : uT);       // hbuf = h1n(T-2)
    if (m == 32) outp[T_LEN - 2] = acc + bo;
    float h1T = tanh_fast(acc);
    hbuf[m] = h1T;                                   // all-lane write
    float acc2 = DOT32(hbuf, w, 0.f);                // h1n(T-1) broadcast
    if (m == 32) outp[T_LEN - 1] = acc2 + bo;
    if (!up) hf[2048 + b * 32 + r] = h1T;            // h_final layer 1
    (void)h1last;
  }
}

extern "C" void kernel_launch(void* const* d_in, const int* in_sizes, int n_in,
                              void* d_out, int out_size, void* d_ws, size_t ws_size,
                              hipStream_t stream) {
  // ws layout: aflag[64] | bflag[64] | pad to 4096 B | uG (64 x RING x 1024 f)
  int*   aflag = (int*)d_ws;
  int*   bflag = aflag + 64;
  float* uG    = (float*)((char*)d_ws + 4096);
  rnn2_split<<<dim3(2 * B_SZ), dim3(64), 0, stream>>>(
      (const float*)d_in[0],  (const float*)d_in[1],  (const float*)d_in[2],
      (const float*)d_in[3],  (const float*)d_in[4],  (const float*)d_in[5],
      (const float*)d_in[6],  (const float*)d_in[7],  (const float*)d_in[8],
      (const float*)d_in[9],  (const float*)d_in[10], (const float*)d_in[11],
      (float*)d_out, aflag, bflag, uG);
}

// Round 14
// 3622.359 us; speedup vs baseline: 1.1187x; 1.1186x over previous
//
#include <hip/hip_runtime.h>

// Two-layer tanh RNN, H=32, B=64, T=16384. Latency-bound sequential scan.
//
// Round-14: R10's 2-wave skeleton + 2-LANES-PER-ROW dots. R13 proved the
// ~560-cyc step is single-chain latency (separate CUs changed nothing), so
// this round shortens the chain: lane pair (2r,2r+1) owns row r; each lane
// does a 16-FMA half-dot (even: cols 0-15, odd: cols 16-31) off 4
// ds_read_b128 (was 8 -> saves the in-order read drain), combined by ONE
// DPP quad_perm(1,0,3,2) add (VALU, no DS). Both roles per wave (A: Whh0
// h0-dot + Wih1 u-dot; B: Whh1 h1-dot + Wout out-dot) use the same 4 reads.
// h-buffers are compact 32-float; all 64 lanes write as 2-way same-address
// duplicates (identical values; 2-way aliasing free). Indexing, u-ring,
// barriers, and epilogues are R10's proven versions.

#define T_LEN 16384
#define B_SZ  64
#define NW    (T_LEN / 32)   // 512 windows

__device__ __forceinline__ float rl(float v, int lane) {
  return __int_as_float(__builtin_amdgcn_readlane(__float_as_int(v), lane));
}

// v + quad_perm([1,0,3,2]) of v : combines the even/odd pair partials.
__device__ __forceinline__ float pair_add(float v) {
  int t = __builtin_amdgcn_update_dpp(0, __float_as_int(v), 0xB1, 0xF, 0xF, true);
  return v + __int_as_float(t);
}

__device__ __forceinline__ float tanh_fast(float v) {
  // tanh(x) = 1 - 2/(exp(2x)+1); saturates correctly at +/-inf.
  float e = __expf(2.0f * v);
  return 1.0f - __fdividef(2.0f, e + 1.0f);
}

// 16-FMA half-dot: this lane's half [q..q+16) of a row, against hp[0..3].
#define HDOT(HP, W) ({                                             \
  float a0_ = 0.f, a1_ = 0.f, a2_ = 0.f, a3_ = 0.f;                \
  _Pragma("unroll")                                                \
  for (int k_ = 0; k_ < 4; ++k_) {                                 \
    float4 hv_ = (HP)[k_];                                         \
    a0_ = fmaf((W)[4*k_],   hv_.x, a0_);                           \
    a1_ = fmaf((W)[4*k_+1], hv_.y, a1_);                           \
    a2_ = fmaf((W)[4*k_+2], hv_.z, a2_);                           \
    a3_ = fmaf((W)[4*k_+3], hv_.w, a3_);                           \
  }                                                                \
  (a0_ + a1_) + (a2_ + a3_); })

__global__ __launch_bounds__(128, 1) void rnn2_kernel(
    const float* __restrict__ x,    const float* __restrict__ hs,
    const float* __restrict__ Wih0, const float* __restrict__ Whh0,
    const float* __restrict__ bih0, const float* __restrict__ bhh0,
    const float* __restrict__ Wih1, const float* __restrict__ Whh1,
    const float* __restrict__ bih1, const float* __restrict__ bhh1,
    const float* __restrict__ Wout, const float* __restrict__ bout,
    float* __restrict__ out)
{
  __shared__ __align__(16) float h0buf[32];      // compact h0n state
  __shared__ __align__(16) float h1buf[32];      // compact h1n state
  __shared__ __align__(16) float uwin[2][1024];  // A->B; slot t2*32 + row

  const int tid = (int)threadIdx.x;
  const int wv  = tid >> 6;            // 0 = wave A (h0), 1 = wave B (h1)
  const int m   = tid & 63;
  const int r   = m >> 1;              // row owned by this lane pair
  const int q   = (m & 1) * 16;        // column half: even lanes 0-15, odd 16-31
  const int b   = (int)blockIdx.x;

  // Per-lane half-rows (16 floats each):
  //  A: wa = Whh0[r][q..), wb2 = Wih1[r][q..).  B: wa = Whh1[r][q..), wb2 = Wout[q..).
  const float* pa = (wv == 0) ? (Whh0 + r * 32 + q) : (Whh1 + r * 32 + q);
  const float* pb = (wv == 0) ? (Wih1 + r * 32 + q) : (Wout + q);
  float wa[16], wb2[16];
#pragma unroll
  for (int k = 0; k < 4; ++k) {
    float4 qa = ((const float4*)pa)[k];
    wa[4*k] = qa.x; wa[4*k+1] = qa.y; wa[4*k+2] = qa.z; wa[4*k+3] = qa.w;
    float4 qb = ((const float4*)pb)[k];
    wb2[4*k] = qb.x; wb2[4*k+1] = qb.y; wb2[4*k+2] = qb.z; wb2[4*k+3] = qb.w;
  }

  float xw = 0.f, bin0 = 0.f, bin1 = 0.f;
  if (wv == 0) {
    xw   = Wih0[r];
    bin0 = bih0[r] + bhh0[r];
    bin1 = bih1[r] + bhh1[r];          // b1 folded into u at publication
  }
  const float bo = bout[0];

  // Init compact state (2-way duplicate writes, identical values).
  if (wv == 0) h0buf[r] = hs[b * 32 + r];
  else         h1buf[r] = hs[2048 + b * 32 + r];
  __syncthreads();

  const float4* hp0 = (const float4*)(h0buf + q);
  const float4* hp1 = (const float4*)(h1buf + q);

  const float* xb   = x + (size_t)b * T_LEN;
  float*       outp = out + (size_t)b * T_LEN;       // outs[b*T + t]
  float*       hf   = out + (size_t)B_SZ * T_LEN;    // h_final [2,B,H]

  float h0last = 0.f, obuf = 0.f;

  for (int wdx = 0; wdx <= NW; ++wdx) {
    if (wv == 0) {
      if (wdx < NW) {
        const int tb = 32 * wdx;
        int xi = tb + m; if (xi > T_LEN - 1) xi = T_LEN - 1;
        float xchunk = xb[xi];              // lanes 0..31 hold x(tb..tb+31)
        float* ub = &uwin[wdx & 1][0];
#pragma unroll 4
        for (int t2 = 0; t2 < 32; ++t2) {
          // h0buf = h0n(tb+t2-1): 4x b128 broadcast (2 addrs/wave, free).
          float ah = HDOT(hp0, wa);         // Whh0 half-dot
          float au = HDOT(hp0, wb2);        // Wih1 half-dot
          float acch = pair_add(ah);        // full row dot (both pair lanes)
          float accu = pair_add(au);
          ub[t2 * 32 + r] = bin1 + accu;    // publish u(t-1) (2-way dup write)
          float xv  = rl(xchunk, t2);
          float h0n = tanh_fast(fmaf(xv, xw, bin0 + acch));
          h0buf[r] = h0n;                   // 2-way dup write; compact state
          h0last = h0n;
        }
      }
    } else {
      if (wdx >= 1) {
        const int wb = wdx - 1;             // steps t = 32*wb-1 .. 32*wb+30
        const float* ub = &uwin[wb & 1][0];
#pragma unroll 4
        for (int t2 = 0; t2 < 32; ++t2) {
          const int t = 32 * wb - 1 + t2;
          float uval = ub[t2 * 32 + r];     // u(t) (2-way broadcast read)
          float ah = HDOT(hp1, wa);         // Whh1 half-dot on h1n(t-1)
          float ao = HDOT(hp1, wb2);        // Wout half-dot
          float acch = pair_add(ah);
          float acco = pair_add(ao);        // = out(t-1) - bo (all lanes)
          float h1n  = tanh_fast(uval + acch);
          obuf = (m == t2) ? acco : obuf;   // lane t2 keeps out(32*wb-2+t2)
          if (t >= 0) h1buf[r] = h1n;       // uniform guard (skips wb=0,t2=0)
        }
        const int idx = 32 * wb - 2 + m;    // lane m<32 holds out(idx)
        if (m < 32 && idx >= 0) outp[idx] = obuf + bo;   // coalesced store
      }
    }
    __syncthreads();   // window handoff (uwin parity swap)
  }

  // Epilogue 1 (wave A): publish u(T-1) from h0n(T-1); store h_final L0.
  if (wv == 0) {
    float au = HDOT(hp0, wb2);
    uwin[0][r] = bin1 + pair_add(au);       // u(T-1)[r]
    if (!(m & 1)) hf[b * 32 + r] = h0last;  // h_final layer 0 = h0n(T-1)
  }
  __syncthreads();

  // Epilogue 2 (wave B): h1n(T-1), out(T-2), out(T-1), h_final L1.
  if (wv == 1) {
    float uT = uwin[0][r];
    float ah = HDOT(hp1, wa);               // h1buf = h1n(T-2)
    float ao = HDOT(hp1, wb2);
    float acch = pair_add(ah);
    float acco = pair_add(ao);              // out(T-2) - bo
    if (m == 0) outp[T_LEN - 2] = acco + bo;
    float h1T = tanh_fast(uT + acch);
    h1buf[r] = h1T;                         // 2-way dup write (in-order DS)
    float ao2 = HDOT(hp1, wb2);             // Wout . h1n(T-1)
    float acco2 = pair_add(ao2);
    if (m == 0) outp[T_LEN - 1] = acco2 + bo;
    if (!(m & 1)) hf[2048 + b * 32 + r] = h1T;  // h_final layer 1
  }
}

extern "C" void kernel_launch(void* const* d_in, const int* in_sizes, int n_in,
                              void* d_out, int out_size, void* d_ws, size_t ws_size,
                              hipStream_t stream) {
  rnn2_kernel<<<dim3(B_SZ), dim3(128), 0, stream>>>(
      (const float*)d_in[0],  (const float*)d_in[1],  (const float*)d_in[2],
      (const float*)d_in[3],  (const float*)d_in[4],  (const float*)d_in[5],
      (const float*)d_in[6],  (const float*)d_in[7],  (const float*)d_in[8],
      (const float*)d_in[9],  (const float*)d_in[10], (const float*)d_in[11],
      (float*)d_out);
}

// Round 16
// 3037.365 us; speedup vs baseline: 1.3341x; 1.1926x over previous
//
#include <hip/hip_runtime.h>

// Two-layer tanh RNN, H=32, B=64, T=16384. Latency-bound sequential scan.
//
// Round-16: R14 (passed, 3622 us) + safe chain shortening. R15's r-space
// transform failed correctness (bug not found by inspection) and is
// abandoned; this round keeps h-space and takes only the mechanical cuts:
//  (1) tanh = 1 - 2*rcp(e+1), e = exp2(v * 2/ln2): one const mul + native
//      v_exp + add + rcp + fma = 5 deps (was 7 with __expf(2v) + fdividef).
//  (2) wave-B u-read software-pipelined one step: issues AFTER the critical
//      4x ds_read_b128 each step, consumed from register next iteration.
//  (3) wave-A: h0buf write (feeds next step's in-order reads) before the
//      u publish; prex = fmaf(xv,xw,bin0) hoisted ahead of the dots.
// Skeleton identical to R14: lane pair (2r,2r+1) owns row r, 16-FMA
// half-dots off 4 ds_read_b128, one quad_perm DPP pair-add, u window ring,
// one barrier per 32-step window, same epilogues.

#define T_LEN 16384
#define B_SZ  64
#define NW    (T_LEN / 32)   // 512 windows

#if __has_builtin(__builtin_amdgcn_exp2f)
#define EXP2(x) __builtin_amdgcn_exp2f(x)
#else
#define EXP2(x) exp2f(x)
#endif

__device__ __forceinline__ float rl(float v, int lane) {
  return __int_as_float(__builtin_amdgcn_readlane(__float_as_int(v), lane));
}

// v + quad_perm([1,0,3,2]) of v : combines the even/odd pair partials.
__device__ __forceinline__ float pair_add(float v) {
  int t = __builtin_amdgcn_update_dpp(0, __float_as_int(v), 0xB1, 0xF, 0xF, true);
  return v + __int_as_float(t);
}

__device__ __forceinline__ float tanh_fast(float v) {
  // tanh(v) = 1 - 2/(e^{2v}+1); e^{2v} = 2^{v*2*log2(e)}. 5-dep chain.
  // Saturates: v->+inf => 1; v->-inf => exp2->0 => rcp(1)=1 => -1.
  float e = EXP2(v * 2.885390082f);
  return fmaf(-2.f, __builtin_amdgcn_rcpf(e + 1.f), 1.f);
}

// 16-FMA half-dot: this lane's half [q..q+16) of a row, against hp[0..3].
#define HDOT(HP, W) ({                                             \
  float a0_ = 0.f, a1_ = 0.f, a2_ = 0.f, a3_ = 0.f;                \
  _Pragma("unroll")                                                \
  for (int k_ = 0; k_ < 4; ++k_) {                                 \
    float4 hv_ = (HP)[k_];                                         \
    a0_ = fmaf((W)[4*k_],   hv_.x, a0_);                           \
    a1_ = fmaf((W)[4*k_+1], hv_.y, a1_);                           \
    a2_ = fmaf((W)[4*k_+2], hv_.z, a2_);                           \
    a3_ = fmaf((W)[4*k_+3], hv_.w, a3_);                           \
  }                                                                \
  (a0_ + a1_) + (a2_ + a3_); })

__global__ __launch_bounds__(128, 1) void rnn2_kernel(
    const float* __restrict__ x,    const float* __restrict__ hs,
    const float* __restrict__ Wih0, const float* __restrict__ Whh0,
    const float* __restrict__ bih0, const float* __restrict__ bhh0,
    const float* __restrict__ Wih1, const float* __restrict__ Whh1,
    const float* __restrict__ bih1, const float* __restrict__ bhh1,
    const float* __restrict__ Wout, const float* __restrict__ bout,
    float* __restrict__ out)
{
  __shared__ __align__(16) float h0buf[32];      // compact h0n state
  __shared__ __align__(16) float h1buf[32];      // compact h1n state
  __shared__ __align__(16) float uwin[2][1024];  // A->B; slot t2*32 + row

  const int tid = (int)threadIdx.x;
  const int wv  = tid >> 6;            // 0 = wave A (h0), 1 = wave B (h1)
  const int m   = tid & 63;
  const int r   = m >> 1;              // row owned by this lane pair
  const int q   = (m & 1) * 16;        // column half: even lanes 0-15, odd 16-31
  const int b   = (int)blockIdx.x;

  // Per-lane half-rows (16 floats each):
  //  A: wa = Whh0[r][q..), wb2 = Wih1[r][q..).  B: wa = Whh1[r][q..), wb2 = Wout[q..).
  const float* pa = (wv == 0) ? (Whh0 + r * 32 + q) : (Whh1 + r * 32 + q);
  const float* pb = (wv == 0) ? (Wih1 + r * 32 + q) : (Wout + q);
  float wa[16], wb2[16];
#pragma unroll
  for (int k = 0; k < 4; ++k) {
    float4 qa = ((const float4*)pa)[k];
    wa[4*k] = qa.x; wa[4*k+1] = qa.y; wa[4*k+2] = qa.z; wa[4*k+3] = qa.w;
    float4 qb = ((const float4*)pb)[k];
    wb2[4*k] = qb.x; wb2[4*k+1] = qb.y; wb2[4*k+2] = qb.z; wb2[4*k+3] = qb.w;
  }

  float xw = 0.f, bin0 = 0.f, bin1 = 0.f;
  if (wv == 0) {
    xw   = Wih0[r];
    bin0 = bih0[r] + bhh0[r];
    bin1 = bih1[r] + bhh1[r];          // b1 folded into u at publication
  }
  const float bo = bout[0];

  // Init compact state (2-way duplicate writes, identical values).
  if (wv == 0) h0buf[r] = hs[b * 32 + r];
  else         h1buf[r] = hs[2048 + b * 32 + r];
  __syncthreads();

  const float4* hp0 = (const float4*)(h0buf + q);
  const float4* hp1 = (const float4*)(h1buf + q);

  const float* xb   = x + (size_t)b * T_LEN;
  float*       outp = out + (size_t)b * T_LEN;       // outs[b*T + t]
  float*       hf   = out + (size_t)B_SZ * T_LEN;    // h_final [2,B,H]

  float h0last = 0.f, obuf = 0.f;

  for (int wdx = 0; wdx <= NW; ++wdx) {
    if (wv == 0) {
      if (wdx < NW) {
        const int tb = 32 * wdx;
        int xi = tb + m; if (xi > T_LEN - 1) xi = T_LEN - 1;
        float xchunk = xb[xi];              // lanes 0..31 hold x(tb..tb+31)
        float* ub = &uwin[wdx & 1][0];
#pragma unroll 4
        for (int t2 = 0; t2 < 32; ++t2) {
          // Off-chain first: x-term (independent of the broadcast reads).
          float xv   = rl(xchunk, t2);
          float prex = fmaf(xv, xw, bin0);
          // h0buf = h0n(tb+t2-1): 4x b128 broadcast (2 addrs/wave, free).
          float ah = HDOT(hp0, wa);         // Whh0 half-dot   (chain)
          float au = HDOT(hp0, wb2);        // Wih1 half-dot   (off-chain)
          float acch = pair_add(ah);
          float h0n  = tanh_fast(prex + acch);
          h0buf[r] = h0n;                   // chain write FIRST (in-order DS)
          float accu = pair_add(au);
          ub[t2 * 32 + r] = bin1 + accu;    // publish u(t-1) (2-way dup write)
          h0last = h0n;
        }
      }
    } else {
      if (wdx >= 1) {
        const int wb = wdx - 1;             // steps t = 32*wb-1 .. 32*wb+30
        const float* ub = &uwin[wb & 1][0];
        float uval = ub[r];                 // preload slot 0 (u at t = 32wb-1)
#pragma unroll 4
        for (int t2 = 0; t2 < 32; ++t2) {
          const int t = 32 * wb - 1 + t2;
          float ah = HDOT(hp1, wa);         // Whh1 half-dot on h1n(t-1) (chain)
          float ao = HDOT(hp1, wb2);        // Wout half-dot (off-chain)
          // Pipelined u-read: issues AFTER the chain reads, used next iter.
          float unext = ub[((t2 + 1) & 31) * 32 + r];
          float acch = pair_add(ah);
          float h1n  = tanh_fast(uval + acch);
          float acco = pair_add(ao);        // = out(t-1) - bo (all lanes)
          obuf = (m == t2) ? acco : obuf;   // lane t2 keeps out(32*wb-2+t2)
          if (t >= 0) h1buf[r] = h1n;       // uniform guard (skips wb=0,t2=0)
          uval = unext;
        }
        const int idx = 32 * wb - 2 + m;    // lane m<32 holds out(idx)
        if (m < 32 && idx >= 0) outp[idx] = obuf + bo;   // coalesced store
      }
    }
    __syncthreads();   // window handoff (uwin parity swap)
  }

  // Epilogue 1 (wave A): publish u(T-1) from h0n(T-1); store h_final L0.
  if (wv == 0) {
    float au = HDOT(hp0, wb2);
    uwin[0][r] = bin1 + pair_add(au);       // u(T-1)[r]
    if (!(m & 1)) hf[b * 32 + r] = h0last;  // h_final layer 0 = h0n(T-1)
  }
  __syncthreads();

  // Epilogue 2 (wave B): h1n(T-1), out(T-2), out(T-1), h_final L1.
  if (wv == 1) {
    float uT = uwin[0][r];
    float ah = HDOT(hp1, wa);               // h1buf = h1n(T-2)
    float ao = HDOT(hp1, wb2);
    float acch = pair_add(ah);
    float acco = pair_add(ao);              // out(T-2) - bo
    if (m == 0) outp[T_LEN - 2] = acco + bo;
    float h1T = tanh_fast(uT + acch);
    h1buf[r] = h1T;                         // 2-way dup write (in-order DS)
    float ao2 = HDOT(hp1, wb2);             // Wout . h1n(T-1)
    float acco2 = pair_add(ao2);
    if (m == 0) outp[T_LEN - 1] = acco2 + bo;
    if (!(m & 1)) hf[2048 + b * 32 + r] = h1T;  // h_final layer 1
  }
}

extern "C" void kernel_launch(void* const* d_in, const int* in_sizes, int n_in,
                              void* d_out, int out_size, void* d_ws, size_t ws_size,
                              hipStream_t stream) {
  rnn2_kernel<<<dim3(B_SZ), dim3(128), 0, stream>>>(
      (const float*)d_in[0],  (const float*)d_in[1],  (const float*)d_in[2],
      (const float*)d_in[3],  (const float*)d_in[4],  (const float*)d_in[5],
      (const float*)d_in[6],  (const float*)d_in[7],  (const float*)d_in[8],
      (const float*)d_in[9],  (const float*)d_in[10], (const float*)d_in[11],
      (float*)d_out);
}